// Round 5
// baseline (189.406 us; speedup 1.0000x reference)
//
#include <hip/hip_runtime.h>

#define RWIN 5
#define TMAX 8192
#define NROW 2048

// Single fused kernel: one wave per (row, window) task, 10240 tasks.
// task -> row = task & 2047 (interleaved so concurrent tasks have i.i.d.
// lengths), win = task >> 11. Each wave pre-issues <=7 independent float4
// loads (clamped addresses -> back-to-back issue, one waitcnt), reduces,
// then the last-arriving wave of each row (device-scope counter) sorts the
// 10 values via shuffles and writes the row. No spinning -> deadlock-free.
__global__ __launch_bounds__(128) void minmax_fused_kernel(
    const float* __restrict__ in, const int* __restrict__ lengths,
    float* __restrict__ vals, int* __restrict__ cnt, float* __restrict__ out)
{
    const int tid  = threadIdx.x;
    const int wv   = tid >> 6;
    const int lane = tid & 63;
    const int task = blockIdx.x * 2 + wv;        // 0..10239
    const int row  = task & (NROW - 1);
    const int win  = task >> 11;                 // 0..4

    const int L = lengths[row];
    const float* rowp = in + (size_t)row * TMAX;
    const int s  = (win * L) / RWIN;                     // window start (incl)
    const int e  = ((win + 1) * L + (RWIN - 1)) / RWIN;  // window end (excl)
    const int sa = s & ~3;                               // aligned start
    const int niter = (e - sa + 255) >> 8;               // 1..7 iterations of 256

    const float NINF = -__builtin_inff();
    const float PINF =  __builtin_inff();
    const int t0 = sa + lane * 4;

    // Pass 1: issue all loads back-to-back into registers (no uses between).
    float4 v[7];
    #pragma unroll
    for (int i = 0; i < 7; ++i) {
        if (i < niter) {
            const int t = t0 + (i << 8);
            v[i] = *reinterpret_cast<const float4*>(rowp + (t < e ? t : sa));
        }
    }

    // Pass 2: reduce. Interior iterations fully live (6 VALU / float4);
    // edge iterations (first & last) per-element masked.
    float mx = NINF, mn = PINF;
    #pragma unroll
    for (int i = 0; i < 7; ++i) {
        if (i < niter) {
            if (i > 0 && i < niter - 1) {
                mx = fmaxf(mx, fmaxf(fmaxf(v[i].x, v[i].y), fmaxf(v[i].z, v[i].w)));
                mn = fminf(mn, fminf(fminf(v[i].x, v[i].y), fminf(v[i].z, v[i].w)));
            } else {
                const int t = t0 + (i << 8);
                const float xs[4] = {v[i].x, v[i].y, v[i].z, v[i].w};
                #pragma unroll
                for (int j = 0; j < 4; ++j) {
                    const int  idx = t + j;
                    const bool ok  = (idx >= s) & (idx < e);
                    mx = fmaxf(mx, ok ? xs[j] : NINF);
                    mn = fminf(mn, ok ? xs[j] : PINF);
                }
            }
        }
    }

    // Wave butterfly reduction.
    #pragma unroll
    for (int off = 1; off < 64; off <<= 1) {
        mx = fmaxf(mx, __shfl_xor(mx, off));
        mn = fminf(mn, __shfl_xor(mn, off));
    }

    // Publish window result; last arrival finishes the row.
    int lastf = 0;
    if (lane == 0) {
        __hip_atomic_store(&vals[row * (2 * RWIN) + win], mx,
                           __ATOMIC_RELAXED, __HIP_MEMORY_SCOPE_AGENT);
        __hip_atomic_store(&vals[row * (2 * RWIN) + RWIN + win], mn,
                           __ATOMIC_RELAXED, __HIP_MEMORY_SCOPE_AGENT);
        const int old = __hip_atomic_fetch_add(&cnt[row], 1,
                           __ATOMIC_ACQ_REL, __HIP_MEMORY_SCOPE_AGENT);
        lastf = (old == RWIN - 1);
    }
    lastf = __builtin_amdgcn_readfirstlane(lastf);
    if (!lastf) return;

    // Finisher wave: lanes 0..9 hold the 10 values; rank sort via shuffles.
    float vv = 0.0f;
    if (lane < 2 * RWIN)
        vv = __hip_atomic_load(&vals[row * (2 * RWIN) + lane],
                               __ATOMIC_RELAXED, __HIP_MEMORY_SCOPE_AGENT);
    int pos = 0;
    #pragma unroll
    for (int k = 0; k < 2 * RWIN; ++k) {
        const float vk = __shfl(vv, k);
        pos += (int)((vk < vv) | ((vk == vv) & (k < lane)));
    }
    if (lane < 2 * RWIN) out[row * (2 * RWIN) + pos] = vv;
    if (lane == 0)
        __hip_atomic_store(&cnt[row], 0, __ATOMIC_RELAXED, __HIP_MEMORY_SCOPE_AGENT);
}

extern "C" void kernel_launch(void* const* d_in, const int* in_sizes, int n_in,
                              void* d_out, int out_size, void* d_ws, size_t ws_size,
                              hipStream_t stream) {
    const float* in      = (const float*)d_in[0];
    const int*   lengths = (const int*)d_in[1];
    float*       out     = (float*)d_out;
    float*       vals    = (float*)d_ws;                       // NROW*10 floats
    int*         cnt     = (int*)((char*)d_ws + NROW * 2 * RWIN * sizeof(float));

    hipMemsetAsync(cnt, 0, NROW * sizeof(int), stream);

    const int ntask  = NROW * RWIN;           // 10240
    const int nblock = ntask / 2;             // 128 threads = 2 waves = 2 tasks
    minmax_fused_kernel<<<nblock, 128, 0, stream>>>(in, lengths, vals, cnt, out);
}

// Round 6
// 11.323 us; speedup vs baseline: 16.7273x; 16.7273x over previous
//
#include <hip/hip_runtime.h>

#define RWIN 5
#define TMAX 8192

// One block per row (proven R2 structure), 320 threads = 5 waves, wave w owns
// window w = [floor(w*L/5), ceil((w+1)*L/5)). Improvements over R2:
//  - all <=7 float4 loads per wave pre-issued into registers (independent
//    addresses, one waitcnt) instead of a serialized load-reduce loop;
//  - masking only on the 2 edge iterations (interior iters are provably
//    fully inside [s,e)), keeping the body at ~8 VALU per float4;
//  - fmax/fmin chains shaped for v_max3/v_min3 fusion.
// No atomics, no second launch.
__global__ __launch_bounds__(5 * 64) void minmax_sort_kernel(
    const float* __restrict__ in, const int* __restrict__ lengths,
    float* __restrict__ out)
{
    __shared__ float sm[2 * RWIN];

    const int b    = blockIdx.x;
    const int tid  = threadIdx.x;
    const int w    = tid >> 6;    // window 0..4
    const int lane = tid & 63;

    const int L = lengths[b];
    const float* rowp = in + (size_t)b * TMAX;

    const int s  = (w * L) / RWIN;                      // start (incl)
    const int e  = ((w + 1) * L + (RWIN - 1)) / RWIN;   // end (excl), >= s+1
    const int sa = s & ~3;                              // aligned start
    const int niter = (e - sa + 255) >> 8;              // 1..7 iters of 256 elems

    const float NINF = -__builtin_inff();
    const float PINF =  __builtin_inff();
    const int t0 = sa + lane * 4;

    // Pass 1: pre-issue all loads back-to-back (wave-uniform guards; tail
    // lanes clamp to sa, which is aligned and in-row).
    float4 v[7];
    #pragma unroll
    for (int i = 0; i < 7; ++i) {
        if (i < niter) {
            const int t = t0 + (i << 8);
            v[i] = *reinterpret_cast<const float4*>(rowp + (t < e ? t : sa));
        }
    }

    // Pass 2: reduce. Interior iterations are fully inside [s,e); only the
    // first and last iteration need per-element masks.
    float mx = NINF, mn = PINF;
    #pragma unroll
    for (int i = 0; i < 7; ++i) {
        if (i < niter) {
            if (i > 0 && i < niter - 1) {
                mx = fmaxf(mx, fmaxf(fmaxf(v[i].x, v[i].y), fmaxf(v[i].z, v[i].w)));
                mn = fminf(mn, fminf(fminf(v[i].x, v[i].y), fminf(v[i].z, v[i].w)));
            } else {
                const int t = t0 + (i << 8);
                const float xs[4] = {v[i].x, v[i].y, v[i].z, v[i].w};
                #pragma unroll
                for (int j = 0; j < 4; ++j) {
                    const int  idx = t + j;
                    const bool ok  = (idx >= s) & (idx < e);
                    mx = fmaxf(mx, ok ? xs[j] : NINF);
                    mn = fminf(mn, ok ? xs[j] : PINF);
                }
            }
        }
    }

    // Wave-level butterfly reduction (64 lanes).
    #pragma unroll
    for (int off = 1; off < 64; off <<= 1) {
        mx = fmaxf(mx, __shfl_xor(mx, off));
        mn = fminf(mn, __shfl_xor(mn, off));
    }
    if (lane == 0) { sm[w] = mx; sm[RWIN + w] = mn; }
    __syncthreads();

    // Rank sort of the 10 values (stable via index tie-break); ascending.
    if (tid < 2 * RWIN) {
        const float vv = sm[tid];
        int pos = 0;
        #pragma unroll
        for (int j = 0; j < 2 * RWIN; ++j) {
            const float vj = sm[j];
            pos += (int)((vj < vv) | ((vj == vv) & (j < tid)));
        }
        out[b * (2 * RWIN) + pos] = vv;
    }
}

extern "C" void kernel_launch(void* const* d_in, const int* in_sizes, int n_in,
                              void* d_out, int out_size, void* d_ws, size_t ws_size,
                              hipStream_t stream) {
    const float* in      = (const float*)d_in[0];
    const int*   lengths = (const int*)d_in[1];
    float*       out     = (float*)d_out;
    const int B = in_sizes[1];   // 2048 rows
    minmax_sort_kernel<<<B, 5 * 64, 0, stream>>>(in, lengths, out);
}